// Round 10
// baseline (135.334 us; speedup 1.0000x reference)
//
#include <hip/hip_runtime.h>

typedef _Float16 f16;
typedef _Float16 f16x2 __attribute__((ext_vector_type(2)));
typedef _Float16 f16x4 __attribute__((ext_vector_type(4)));
typedef _Float16 f16x8 __attribute__((ext_vector_type(8)));
typedef float f32x4 __attribute__((ext_vector_type(4)));
typedef float f32x16 __attribute__((ext_vector_type(16)));
typedef unsigned int u32;
typedef unsigned int u32x4 __attribute__((ext_vector_type(4)));

__device__ inline f32x16 mfma32(f16x8 a, f16x8 b, f32x16 c) {
    return __builtin_amdgcn_mfma_f32_32x32x16_f16(a, b, c, 0, 0, 0);
}

__device__ inline u32 pk2u(float a, float b) {
    return __builtin_bit_cast(u32, __builtin_amdgcn_cvt_pkrtz(a, b));
}

// async global->LDS, 16 B per lane; LDS dest = wave-uniform base + lane*16B
__device__ inline void gl16(const f16* g, f16* l) {
    __builtin_amdgcn_global_load_lds(
        (const __attribute__((address_space(1))) void*)g,
        (__attribute__((address_space(3))) void*)l, 16, 0, 0);
}

// ---------------------------------------------------------------------------
// Kernel 1: merged prep. blocks [0,1536): weight norm -> w f16.
//           blocks [1536, 5632): transpose x (B,C,N) fp32 -> xT (B,N,C) f16.
// ---------------------------------------------------------------------------
__global__ __launch_bounds__(256) void prep_k(const float* __restrict__ pv,
                                              const float* __restrict__ pg,
                                              f16* __restrict__ w,
                                              const float* __restrict__ x,
                                              f16* __restrict__ xT) {
    int bid = blockIdx.x;
    if (bid < 1536) {
        int o = bid;
        const float* row = pv + (size_t)o * 512;
        float s = 0.f;
        for (int c = threadIdx.x; c < 512; c += 256) { float t = row[c]; s += t * t; }
        for (int off = 32; off; off >>= 1) s += __shfl_down(s, off, 64);
        __shared__ float red[4];
        int lane = threadIdx.x & 63, wid = threadIdx.x >> 6;
        if (lane == 0) red[wid] = s;
        __syncthreads();
        float tot = red[0] + red[1] + red[2] + red[3];
        float scale = pg[o] * rsqrtf(tot);
        for (int c = threadIdx.x; c < 512; c += 256)
            w[(size_t)o * 512 + c] = (f16)(row[c] * scale);
    } else {
        int t2 = bid - 1536;
        int n0 = (t2 & 31) * 32, c0 = ((t2 >> 5) & 15) * 32, b = t2 >> 9;
        int tx = threadIdx.x & 31, ty = threadIdx.x >> 5;  // 32 x 8
        __shared__ float t[32][33];
        const float* xb = x + (size_t)b * 512 * 1024;
        for (int i = 0; i < 4; i++)
            t[ty + 8 * i][tx] = xb[(size_t)(c0 + ty + 8 * i) * 1024 + n0 + tx];
        __syncthreads();
        f16* xTb = xT + (size_t)b * 1024 * 512;
        for (int i = 0; i < 4; i++)
            xTb[(size_t)(n0 + ty + 8 * i) * 512 + c0 + tx] = (f16)t[tx][ty + 8 * i];
    }
}

// ---------------------------------------------------------------------------
// Kernel 3: QKV GEMM (frozen R7 state): 32x32x16 MFMA, BK=64, staging via
//   global_load_lds_dwordx4, XOR swizzle pre-applied on the GLOBAL source.
// ---------------------------------------------------------------------------
__global__ __launch_bounds__(256) void qkv_gemm_k(const f16* __restrict__ w,
                                                  const f16* __restrict__ xT,
                                                  const float* __restrict__ pb,
                                                  f16* __restrict__ qk,
                                                  f16* __restrict__ v) {
    __shared__ f16 lA[128 * 64];   // 16 KB
    __shared__ f16 lB[128 * 64];   // 16 KB
    int b = blockIdx.z;
    int oBase = blockIdx.y * 128;
    int nBase = blockIdx.x * 128;
    const f16* xb = xT + (size_t)b * 1024 * 512;
    int tid = threadIdx.x, lane = tid & 63, warp = tid >> 6;
    int wy = warp >> 1, wx = warp & 1;
    int l31 = lane & 31, hi = lane >> 5;

    int srow = lane >> 3;
    int phys = lane & 7;
    int schunk = phys ^ srow;
    const f16* aS[4]; const f16* bS[4]; f16* dA[4]; f16* dB[4];
    for (int j = 0; j < 4; j++) {
        int rb = (warp * 4 + j) * 8;
        aS[j] = w  + (size_t)(oBase + rb + srow) * 512 + schunk * 8;
        bS[j] = xb + (size_t)(nBase + rb + srow) * 512 + schunk * 8;
        dA[j] = &lA[rb * 64];   // + lane*8 f16 done by HW (lane x 16 B)
        dB[j] = &lB[rb * 64];
    }
    int phk[4];
    for (int ks = 0; ks < 4; ks++)
        phk[ks] = (((ks * 2 + hi) ^ (l31 & 7))) * 8;

    f32x16 acc[2][2] = {};

    for (int i = 0; i < 8; i++) {
        int k0 = i * 64;
        __syncthreads();                 // prev tile's reads done
        for (int j = 0; j < 4; j++) {
            gl16(aS[j] + k0, dA[j]);
            gl16(bS[j] + k0, dB[j]);
        }
        __syncthreads();                 // implicit vmcnt(0) drain (m97)
        for (int ks = 0; ks < 4; ks++) {
            f16x8 af[2], bf[2];
            for (int mi = 0; mi < 2; mi++)
                af[mi] = *(f16x8*)&lA[(wy * 64 + mi * 32 + l31) * 64 + phk[ks]];
            for (int ni = 0; ni < 2; ni++)
                bf[ni] = *(f16x8*)&lB[(wx * 64 + ni * 32 + l31) * 64 + phk[ks]];
            for (int mi = 0; mi < 2; mi++)
                for (int ni = 0; ni < 2; ni++)
                    acc[mi][ni] = mfma32(af[mi], bf[ni], acc[mi][ni]);
        }
    }

    int selB = oBase >> 9;
    for (int mi = 0; mi < 2; mi++) {
        for (int g = 0; g < 4; g++) {
            int oR = oBase + wy * 64 + mi * 32 + 8 * g + 4 * hi;
            int h = (oR >> 6) & 7, d0 = oR & 63;
            for (int ni = 0; ni < 2; ni++) {
                int n = nBase + wx * 64 + ni * 32 + l31;
                if (selB < 2) {
                    float sc = selB == 0 ? 0.125f : 1.0f;  // fold 1/sqrt(64)
                    f16x4 o4;
                    for (int r = 0; r < 4; r++)
                        o4[r] = (f16)((acc[mi][ni][g * 4 + r] + pb[oR + r]) * sc);
                    *(f16x4*)&qk[((((size_t)b * 2 + selB) * 8 + h) * 1024 + n) * 64 + d0] = o4;
                } else {
                    for (int r = 0; r < 4; r++) {
                        float val = acc[mi][ni][g * 4 + r] + pb[oR + r];
                        v[(((size_t)b * 8 + h) * 64 + d0 + r) * 1024 + n] = (f16)val;
                    }
                }
            }
        }
    }
}

// ---------------------------------------------------------------------------
// Kernel 4: fused attention + residual.  v10: SINGLE-WAVE blocks, ZERO
//   barriers.  Six 4-wave variants (R0/R3/R6/R8/R9) all pinned at ~36 us;
//   the shared invariant was __syncthreads lockstep (full vmcnt/lgkm drain
//   + slowest-wave reconvergence every iteration).  Here: one wave = one
//   32q tile; K/V staged via gl16 into WAVE-PRIVATE LDS (KVBLK=32: K-tile
//   32x64 + V-tile 64x32, double-buffered = 16 KB/block); per-iteration
//   sync is ONE counted `s_waitcnt vmcnt(8)` (T4: issue next tile's 8
//   gl16s first, wait only for the current tile's 8; never drain to 0).
//   Grid 64 bh x 32 q = 2048 blocks = 8 blocks/CU (LDS 128/160 KB) =
//   2 waves/SIMD.  Balanced XOR swizzles (K: chunk^=row&7; V: ^=row&3)
//   keep b128 reads at the 8-cycle BW floor.  Per-iter math = R9 body
//   with mt fixed; totals conserved (absmax must stay 0.015625).
// ---------------------------------------------------------------------------
__global__ __launch_bounds__(64, 2) void attn_k(const f16* __restrict__ qk,
                                                const f16* __restrict__ vg,
                                                const float* __restrict__ x,
                                                float* __restrict__ out) {
    __shared__ __align__(16) f16 smem[8192];   // 2 buf x (K 2048 + V 2048) f16
    int bh = blockIdx.x;
    int b = bh >> 3, h = bh & 7;
    int tid = threadIdx.x;            // 0..63 (one wave)
    int l31 = tid & 31, hi = tid >> 5;

    const f16* qbase = qk + (((size_t)b * 2 + 0) * 8 + h) * 1024 * 64;
    const f16* kbase = qk + (((size_t)b * 2 + 1) * 8 + h) * 1024 * 64;
    const f16* vbase = vg + ((size_t)b * 8 + h) * 64 * 1024;

    int q0 = blockIdx.y * 32;
    f16x8 aq[4];
    for (int ks = 0; ks < 4; ks++)
        aq[ks] = *(const f16x8*)&qbase[(size_t)(q0 + l31) * 64 + ks * 16 + hi * 8];

    // staging geometry (per gl16: lane tid writes dest base + tid*16B)
    // K-tile [32 kv][64 d], rows 128 B; instr j covers rows [8j,8j+8):
    //   lane: row 8j+(tid>>3), phys chunk tid&7, global chunk ^= row&7
    int kr = tid >> 3, kch = (tid & 7) ^ kr;
    const f16* kS = kbase + (size_t)kr * 64 + kch * 8;
    // V-tile [64 d][32 kv], rows 64 B; instr j covers rows [16j,16j+16):
    //   lane: row 16j+(tid>>2), phys chunk tid&3, global chunk ^= row&3
    int vr = tid >> 2, vch = (tid & 3) ^ (vr & 3);
    const f16* vS = vbase + (size_t)vr * 1024 + vch * 8;

#define STAGE(BUF, KT)                                                        \
    do {                                                                      \
        f16* lbK = smem + (BUF) * 4096;                                       \
        f16* lbV = lbK + 2048;                                                \
        const f16* ks_ = kS + (size_t)(KT) * 32 * 64;                         \
        const f16* vs_ = vS + (size_t)(KT) * 32;                              \
        gl16(ks_,            lbK);                                            \
        gl16(ks_ + 8 * 64,   lbK + 512);                                      \
        gl16(ks_ + 16 * 64,  lbK + 1024);                                     \
        gl16(ks_ + 24 * 64,  lbK + 1536);                                     \
        gl16(vs_,              lbV);                                          \
        gl16(vs_ + 16 * 1024,  lbV + 512);                                    \
        gl16(vs_ + 32 * 1024,  lbV + 1024);                                   \
        gl16(vs_ + 48 * 1024,  lbV + 1536);                                   \
    } while (0)

    f32x16 accO[2] = {};
    float l_acc = 0.f;

    // prologue: tile 0 -> buf 0 (8 gl16 outstanding; aq loads also pending,
    // drained by the first counted wait since they are older)
    STAGE(0, 0);

    for (int kt = 0; kt < 32; kt++) {
        int cur = kt & 1;
        if (kt < 31) {
            STAGE(cur ^ 1, kt + 1);                      // 8 newer in flight
            asm volatile("s_waitcnt vmcnt(8)" ::: "memory");  // cur's 8 done
        } else {
            asm volatile("s_waitcnt vmcnt(0)" ::: "memory");
        }
        const f16* lK = smem + cur * 4096;
        const f16* lV = lK + 2048;

        // S^T (32 kv x 32 q): p = exp(s) packed to f16x2 pairs in registers
        // P0[g] = kv pair {8g+4hi+0,1}, P1 = {8g+4hi+2,3} (col q = l31)
        f16x8 ak[4];
        for (int ks = 0; ks < 4; ks++)
            ak[ks] = *(const f16x8*)&lK[l31 * 64 + (((ks * 2 + hi) ^ (l31 & 7)) << 3)];
        f32x16 stt = {};
        for (int ks = 0; ks < 4; ks++)
            stt = mfma32(ak[ks], aq[ks], stt);
        u32 P0[4], P1[4];
        float rs = 0.f;
        for (int g = 0; g < 4; g++) {
            float p0 = __expf(stt[g * 4 + 0]);
            float p1 = __expf(stt[g * 4 + 1]);
            float p2 = __expf(stt[g * 4 + 2]);
            float p3 = __expf(stt[g * 4 + 3]);
            rs += (p0 + p1) + (p2 + p3);
            P0[g] = pk2u(p0, p1);
            P1[g] = pk2u(p2, p3);
        }
        l_acc += rs;

        // PV: B-frag for ks2: j0-3 from lane (q,0), j4-7 from (q,1),
        // both with g = 2*ks2+hi_dest.  Send g = 2*ks2+(hi^1).
        f16x8 av[2][2];
        for (int dt = 0; dt < 2; dt++)
            for (int ks2 = 0; ks2 < 2; ks2++) {
                int row = dt * 32 + l31;
                av[dt][ks2] = *(const f16x8*)&lV[row * 32 + (((ks2 * 2 + hi) ^ (l31 & 3)) << 3)];
            }
        f16x8 bfrag[2];
        for (int ks2 = 0; ks2 < 2; ks2++) {
            int ge = 2 * ks2;
            u32 e00 = P0[ge], e01 = P0[ge + 1];
            u32 e10 = P1[ge], e11 = P1[ge + 1];
            u32 k0 = hi ? e01 : e00;       // keep: g = ge + hi
            u32 k1 = hi ? e11 : e10;
            u32 s0 = hi ? e00 : e01;       // send: g = ge + (hi^1)
            u32 s1 = hi ? e10 : e11;
            u32 r0 = __shfl_xor(s0, 32, 64);
            u32 r1 = __shfl_xor(s1, 32, 64);
            u32 a0 = hi ? r0 : k0, a1 = hi ? r1 : k1;   // from (q,0)
            u32 b0 = hi ? k0 : r0, b1 = hi ? k1 : r1;   // from (q,1)
            u32x4 t = {a0, a1, b0, b1};
            bfrag[ks2] = __builtin_bit_cast(f16x8, t);
        }
        for (int dt = 0; dt < 2; dt++)
            for (int ks2 = 0; ks2 < 2; ks2++)
                accO[dt] = mfma32(av[dt][ks2], bfrag[ks2], accO[dt]);
    }
#undef STAGE

    // epilogue: l = own + partner halves; direct 2-segment coalesced stores
    float lt = l_acc + __shfl_xor(l_acc, 32, 64);
    float rl = 1.0f / lt;
    int q = q0 + l31;
    for (int dt = 0; dt < 2; dt++)
        for (int g = 0; g < 4; g++)
            for (int r = 0; r < 4; r++) {
                int d = dt * 32 + 8 * g + 4 * hi + r;
                size_t gi = ((size_t)b * 512 + h * 64 + d) * 1024 + q;
                out[gi] = x[gi] + accO[dt][g * 4 + r] * rl;
            }
}

// ---------------------------------------------------------------------------
extern "C" void kernel_launch(void* const* d_in, const int* in_sizes, int n_in,
                              void* d_out, int out_size, void* d_ws, size_t ws_size,
                              hipStream_t stream) {
    (void)in_sizes; (void)n_in; (void)out_size; (void)ws_size;
    const float* x  = (const float*)d_in[0];
    const float* pv = (const float*)d_in[1];
    const float* pg = (const float*)d_in[2];
    const float* pb = (const float*)d_in[3];
    float* out = (float*)d_out;

    char* ws = (char*)d_ws;
    f16* w   = (f16*)(ws);                                   // 1,572,864 B
    f16* xT  = (f16*)(ws + 1572864);                         // 8,388,608 B
    f16* qk  = (f16*)(ws + 1572864 + 8388608);               // 16,777,216 B
    f16* v   = (f16*)(ws + 1572864 + 8388608 + 16777216);    // 8,388,608 B

    hipLaunchKernelGGL(prep_k,     dim3(5632),     dim3(256), 0, stream, pv, pg, w, x, xT);
    hipLaunchKernelGGL(qkv_gemm_k, dim3(8, 12, 8), dim3(256), 0, stream, w, xT, pb, qk, v);
    hipLaunchKernelGGL(attn_k,     dim3(64, 32),   dim3(64),  0, stream, qk, v, x, out);
}

// Round 11
// 132.170 us; speedup vs baseline: 1.0239x; 1.0239x over previous
//
#include <hip/hip_runtime.h>

typedef _Float16 f16;
typedef _Float16 f16x2 __attribute__((ext_vector_type(2)));
typedef _Float16 f16x4 __attribute__((ext_vector_type(4)));
typedef _Float16 f16x8 __attribute__((ext_vector_type(8)));
typedef float f32x4 __attribute__((ext_vector_type(4)));
typedef float f32x16 __attribute__((ext_vector_type(16)));
typedef unsigned int u32;
typedef unsigned int u32x4 __attribute__((ext_vector_type(4)));

__device__ inline f32x16 mfma32(f16x8 a, f16x8 b, f32x16 c) {
    return __builtin_amdgcn_mfma_f32_32x32x16_f16(a, b, c, 0, 0, 0);
}

__device__ inline u32 pk2u(float a, float b) {
    return __builtin_bit_cast(u32, __builtin_amdgcn_cvt_pkrtz(a, b));
}

// async global->LDS, 16 B per lane; LDS dest = wave-uniform base + lane*16B
__device__ inline void gl16(const f16* g, f16* l) {
    __builtin_amdgcn_global_load_lds(
        (const __attribute__((address_space(1))) void*)g,
        (__attribute__((address_space(3))) void*)l, 16, 0, 0);
}

// ---------------------------------------------------------------------------
// Kernel 1: merged prep. blocks [0,1536): weight norm -> w f16.
//           blocks [1536, 5632): transpose x (B,C,N) fp32 -> xT (B,N,C) f16.
// ---------------------------------------------------------------------------
__global__ __launch_bounds__(256) void prep_k(const float* __restrict__ pv,
                                              const float* __restrict__ pg,
                                              f16* __restrict__ w,
                                              const float* __restrict__ x,
                                              f16* __restrict__ xT) {
    int bid = blockIdx.x;
    if (bid < 1536) {
        int o = bid;
        const float* row = pv + (size_t)o * 512;
        float s = 0.f;
        for (int c = threadIdx.x; c < 512; c += 256) { float t = row[c]; s += t * t; }
        for (int off = 32; off; off >>= 1) s += __shfl_down(s, off, 64);
        __shared__ float red[4];
        int lane = threadIdx.x & 63, wid = threadIdx.x >> 6;
        if (lane == 0) red[wid] = s;
        __syncthreads();
        float tot = red[0] + red[1] + red[2] + red[3];
        float scale = pg[o] * rsqrtf(tot);
        for (int c = threadIdx.x; c < 512; c += 256)
            w[(size_t)o * 512 + c] = (f16)(row[c] * scale);
    } else {
        int t2 = bid - 1536;
        int n0 = (t2 & 31) * 32, c0 = ((t2 >> 5) & 15) * 32, b = t2 >> 9;
        int tx = threadIdx.x & 31, ty = threadIdx.x >> 5;  // 32 x 8
        __shared__ float t[32][33];
        const float* xb = x + (size_t)b * 512 * 1024;
        for (int i = 0; i < 4; i++)
            t[ty + 8 * i][tx] = xb[(size_t)(c0 + ty + 8 * i) * 1024 + n0 + tx];
        __syncthreads();
        f16* xTb = xT + (size_t)b * 1024 * 512;
        for (int i = 0; i < 4; i++)
            xTb[(size_t)(n0 + ty + 8 * i) * 512 + c0 + tx] = (f16)t[tx][ty + 8 * i];
    }
}

// ---------------------------------------------------------------------------
// Kernel 3: QKV GEMM (frozen R7 state): 32x32x16 MFMA, BK=64, staging via
//   global_load_lds_dwordx4, XOR swizzle pre-applied on the GLOBAL source.
// ---------------------------------------------------------------------------
__global__ __launch_bounds__(256) void qkv_gemm_k(const f16* __restrict__ w,
                                                  const f16* __restrict__ xT,
                                                  const float* __restrict__ pb,
                                                  f16* __restrict__ qk,
                                                  f16* __restrict__ v) {
    __shared__ f16 lA[128 * 64];   // 16 KB
    __shared__ f16 lB[128 * 64];   // 16 KB
    int b = blockIdx.z;
    int oBase = blockIdx.y * 128;
    int nBase = blockIdx.x * 128;
    const f16* xb = xT + (size_t)b * 1024 * 512;
    int tid = threadIdx.x, lane = tid & 63, warp = tid >> 6;
    int wy = warp >> 1, wx = warp & 1;
    int l31 = lane & 31, hi = lane >> 5;

    int srow = lane >> 3;
    int phys = lane & 7;
    int schunk = phys ^ srow;
    const f16* aS[4]; const f16* bS[4]; f16* dA[4]; f16* dB[4];
    for (int j = 0; j < 4; j++) {
        int rb = (warp * 4 + j) * 8;
        aS[j] = w  + (size_t)(oBase + rb + srow) * 512 + schunk * 8;
        bS[j] = xb + (size_t)(nBase + rb + srow) * 512 + schunk * 8;
        dA[j] = &lA[rb * 64];   // + lane*8 f16 done by HW (lane x 16 B)
        dB[j] = &lB[rb * 64];
    }
    int phk[4];
    for (int ks = 0; ks < 4; ks++)
        phk[ks] = (((ks * 2 + hi) ^ (l31 & 7))) * 8;

    f32x16 acc[2][2] = {};

    for (int i = 0; i < 8; i++) {
        int k0 = i * 64;
        __syncthreads();                 // prev tile's reads done
        for (int j = 0; j < 4; j++) {
            gl16(aS[j] + k0, dA[j]);
            gl16(bS[j] + k0, dB[j]);
        }
        __syncthreads();                 // implicit vmcnt(0) drain (m97)
        for (int ks = 0; ks < 4; ks++) {
            f16x8 af[2], bf[2];
            for (int mi = 0; mi < 2; mi++)
                af[mi] = *(f16x8*)&lA[(wy * 64 + mi * 32 + l31) * 64 + phk[ks]];
            for (int ni = 0; ni < 2; ni++)
                bf[ni] = *(f16x8*)&lB[(wx * 64 + ni * 32 + l31) * 64 + phk[ks]];
            for (int mi = 0; mi < 2; mi++)
                for (int ni = 0; ni < 2; ni++)
                    acc[mi][ni] = mfma32(af[mi], bf[ni], acc[mi][ni]);
        }
    }

    int selB = oBase >> 9;
    for (int mi = 0; mi < 2; mi++) {
        for (int g = 0; g < 4; g++) {
            int oR = oBase + wy * 64 + mi * 32 + 8 * g + 4 * hi;
            int h = (oR >> 6) & 7, d0 = oR & 63;
            for (int ni = 0; ni < 2; ni++) {
                int n = nBase + wx * 64 + ni * 32 + l31;
                if (selB < 2) {
                    float sc = selB == 0 ? 0.125f : 1.0f;  // fold 1/sqrt(64)
                    f16x4 o4;
                    for (int r = 0; r < 4; r++)
                        o4[r] = (f16)((acc[mi][ni][g * 4 + r] + pb[oR + r]) * sc);
                    *(f16x4*)&qk[((((size_t)b * 2 + selB) * 8 + h) * 1024 + n) * 64 + d0] = o4;
                } else {
                    for (int r = 0; r < 4; r++) {
                        float val = acc[mi][ni][g * 4 + r] + pb[oR + r];
                        v[(((size_t)b * 8 + h) * 64 + d0 + r) * 1024 + n] = (f16)val;
                    }
                }
            }
        }
    }
}

// ---------------------------------------------------------------------------
// Kernel 4: fused attention + residual.  v11 = R9 (best measured) pushed
//   along its proven axis: KVBLK=128 as 2x [64][64] subtiles, gl16 dbuf,
//   ONE barrier per 128-kv iteration (barrier drains 16 -> 9).  Both
//   halves chain into the SAME accumulator (no R8-style register staging,
//   no extra acc -> no spill).  T5 setprio around MFMA clusters (m191:
//   +4-7% on attn; R10's failure was single-wave, not the counted-sync
//   idea).  R10's 4.2M bank conflicts came from 1-wave blocks exposing
//   the 4-way residual; here 4 waves re-cover it (R9 level).
//   LDS 2 buf x [K0 K1 V0 V1] x 8 KB = 64 KB -> still 2 blocks/CU.
//   Per-subtile staging/read addressing is bit-identical to R9.
// ---------------------------------------------------------------------------
#define TSZ 4096   // 64x64 f16 subtile

__global__ __launch_bounds__(256, 2) void attn_k(const f16* __restrict__ qk,
                                                 const f16* __restrict__ vg,
                                                 const float* __restrict__ x,
                                                 float* __restrict__ out) {
    __shared__ __align__(16) f16 smem[8 * TSZ];   // [buf][K0,K1,V0,V1] = 64 KB
    int bh = blockIdx.y;
    int b = bh >> 3, h = bh & 7;
    int qBase = blockIdx.x * 128;
    int tid = threadIdx.x, lane = tid & 63, warp = tid >> 6;
    int l31 = lane & 31, hi = lane >> 5;

    const f16* qbase = qk + (((size_t)b * 2 + 0) * 8 + h) * 1024 * 64;
    const f16* kbase = qk + (((size_t)b * 2 + 1) * 8 + h) * 1024 * 64;
    const f16* vbase = vg + ((size_t)b * 8 + h) * 64 * 1024;

    int q0 = qBase + warp * 32;
    f16x8 aq[4];
    for (int ks = 0; ks < 4; ks++)
        aq[ks] = *(const f16x8*)&qbase[(size_t)(q0 + l31) * 64 + ks * 16 + hi * 8];

    // staging geometry (per gl16: lane tid writes dest base + lane*16B)
    // wave w covers rows [8w,8w+8) and [32+8w,+8) of each 64x64 subtile;
    // global chunk pre-swizzled: (lane&7) ^ (lane>>3)
    int rb = lane >> 3;
    int gchunk = (lane & 7) ^ rb;
    const f16* kS0 = kbase + (size_t)(warp * 8 + rb) * 64 + gchunk * 8;
    const f16* vS0 = vbase + (size_t)(warp * 8 + rb) * 1024 + gchunk * 8;

    f32x16 accO[2] = {};
    float l_acc = 0.f;

    // STAGE one 128-kv tile (two 64-kv halves) into buf: 16 gl16, 0 VGPRs
#define STAGE(BUF, KT2)                                                       \
    do {                                                                      \
        f16* lb = smem + (BUF) * 4 * TSZ;                                     \
        const f16* k0_ = kS0 + (size_t)(2 * (KT2)) * 4096;                    \
        const f16* k1_ = k0_ + 4096;                                          \
        const f16* v0_ = vS0 + (size_t)(2 * (KT2)) * 64;                      \
        const f16* v1_ = v0_ + 64;                                            \
        gl16(k0_,            lb + warp * 512);                                \
        gl16(k0_ + 32 * 64,  lb + 2048 + warp * 512);                         \
        gl16(k1_,            lb + TSZ + warp * 512);                          \
        gl16(k1_ + 32 * 64,  lb + TSZ + 2048 + warp * 512);                   \
        gl16(v0_,              lb + 2 * TSZ + warp * 512);                    \
        gl16(v0_ + 32 * 1024,  lb + 2 * TSZ + 2048 + warp * 512);             \
        gl16(v1_,              lb + 3 * TSZ + warp * 512);                    \
        gl16(v1_ + 32 * 1024,  lb + 3 * TSZ + 2048 + warp * 512);             \
    } while (0)

    // prologue: tile 0 -> buf 0
    STAGE(0, 0);
    __syncthreads();   // implicit vmcnt(0): buf0 ready

    for (int kt2 = 0; kt2 < 8; kt2++) {
        int cur = kt2 & 1;
        if (kt2 < 7) STAGE(cur ^ 1, kt2 + 1);   // async, lands by next barrier

        for (int half = 0; half < 2; half++) {
            const f16* lK = smem + cur * 4 * TSZ + half * TSZ;
            const f16* lV = smem + cur * 4 * TSZ + (2 + half) * TSZ;

            // S^T per mt; p = exp(s) packed to f16x2 pairs in registers:
            // P0[mt][g] = k-pair {8g+4hi+0,1}, P1 = {8g+4hi+2,3} (col q=l31)
            u32 P0[2][4], P1[2][4];
            float rs = 0.f;
            for (int mt = 0; mt < 2; mt++) {
                f16x8 ak[4];
                for (int ks = 0; ks < 4; ks++) {
                    int row = mt * 32 + l31;
                    ak[ks] = *(const f16x8*)&lK[row * 64 + (((ks * 2 + hi) ^ (l31 & 7)) << 3)];
                }
                __builtin_amdgcn_s_setprio(1);
                f32x16 stt = {};
                for (int ks = 0; ks < 4; ks++)
                    stt = mfma32(ak[ks], aq[ks], stt);
                __builtin_amdgcn_s_setprio(0);
                for (int g = 0; g < 4; g++) {
                    float p0 = __expf(stt[g * 4 + 0]);
                    float p1 = __expf(stt[g * 4 + 1]);
                    float p2 = __expf(stt[g * 4 + 2]);
                    float p3 = __expf(stt[g * 4 + 3]);
                    rs += (p0 + p1) + (p2 + p3);
                    P0[mt][g] = pk2u(p0, p1);
                    P1[mt][g] = pk2u(p2, p3);
                }
            }
            l_acc += rs;

            // PV: B-frag for ks: mt=ks>>1; j0-3 from (q,0), j4-7 from (q,1)
            f16x8 av[2][4];
            for (int dt = 0; dt < 2; dt++)
                for (int ks = 0; ks < 4; ks++) {
                    int row = dt * 32 + l31;
                    av[dt][ks] = *(const f16x8*)&lV[row * 64 + (((ks * 2 + hi) ^ (l31 & 7)) << 3)];
                }
            f16x8 bfrag[4];
            for (int ks = 0; ks < 4; ks++) {
                int mt = ks >> 1, ge = 2 * (ks & 1);
                u32 e00 = P0[mt][ge], e01 = P0[mt][ge + 1];
                u32 e10 = P1[mt][ge], e11 = P1[mt][ge + 1];
                u32 k0 = hi ? e01 : e00;       // keep: g = ge + hi
                u32 k1 = hi ? e11 : e10;
                u32 s0 = hi ? e00 : e01;       // send: g = ge + (hi^1)
                u32 s1 = hi ? e10 : e11;
                u32 r0 = __shfl_xor(s0, 32, 64);
                u32 r1 = __shfl_xor(s1, 32, 64);
                u32 a0 = hi ? r0 : k0, a1 = hi ? r1 : k1;   // from (q,0)
                u32 b0 = hi ? k0 : r0, b1 = hi ? k1 : r1;   // from (q,1)
                u32x4 t = {a0, a1, b0, b1};
                bfrag[ks] = __builtin_bit_cast(f16x8, t);
            }
            __builtin_amdgcn_s_setprio(1);
            for (int dt = 0; dt < 2; dt++)
                for (int ks = 0; ks < 4; ks++)
                    accO[dt] = mfma32(av[dt][ks], bfrag[ks], accO[dt]);
            __builtin_amdgcn_s_setprio(0);
        }

        __syncthreads();   // buf[cur] reads done; buf[cur^1] staged (vmcnt 0)
    }
#undef STAGE

    // epilogue: l = own + partner halves; direct 2-segment coalesced stores
    float lt = l_acc + __shfl_xor(l_acc, 32, 64);
    float rl = 1.0f / lt;
    int q = q0 + l31;
    for (int dt = 0; dt < 2; dt++)
        for (int g = 0; g < 4; g++)
            for (int r = 0; r < 4; r++) {
                int d = dt * 32 + 8 * g + 4 * hi + r;
                size_t gi = ((size_t)b * 512 + h * 64 + d) * 1024 + q;
                out[gi] = x[gi] + accO[dt][g * 4 + r] * rl;
            }
}

// ---------------------------------------------------------------------------
extern "C" void kernel_launch(void* const* d_in, const int* in_sizes, int n_in,
                              void* d_out, int out_size, void* d_ws, size_t ws_size,
                              hipStream_t stream) {
    (void)in_sizes; (void)n_in; (void)out_size; (void)ws_size;
    const float* x  = (const float*)d_in[0];
    const float* pv = (const float*)d_in[1];
    const float* pg = (const float*)d_in[2];
    const float* pb = (const float*)d_in[3];
    float* out = (float*)d_out;

    char* ws = (char*)d_ws;
    f16* w   = (f16*)(ws);                                   // 1,572,864 B
    f16* xT  = (f16*)(ws + 1572864);                         // 8,388,608 B
    f16* qk  = (f16*)(ws + 1572864 + 8388608);               // 16,777,216 B
    f16* v   = (f16*)(ws + 1572864 + 8388608 + 16777216);    // 8,388,608 B

    hipLaunchKernelGGL(prep_k,     dim3(5632),     dim3(256), 0, stream, pv, pg, w, x, xT);
    hipLaunchKernelGGL(qkv_gemm_k, dim3(8, 12, 8), dim3(256), 0, stream, w, xT, pb, qk, v);
    hipLaunchKernelGGL(attn_k,     dim3(8, 64),    dim3(256), 0, stream, qk, v, x, out);
}

// Round 12
// 130.585 us; speedup vs baseline: 1.0364x; 1.0121x over previous
//
#include <hip/hip_runtime.h>

typedef _Float16 f16;
typedef _Float16 f16x2 __attribute__((ext_vector_type(2)));
typedef _Float16 f16x4 __attribute__((ext_vector_type(4)));
typedef _Float16 f16x8 __attribute__((ext_vector_type(8)));
typedef float f32x4 __attribute__((ext_vector_type(4)));
typedef float f32x16 __attribute__((ext_vector_type(16)));
typedef unsigned int u32;
typedef unsigned int u32x4 __attribute__((ext_vector_type(4)));

__device__ inline f32x16 mfma32(f16x8 a, f16x8 b, f32x16 c) {
    return __builtin_amdgcn_mfma_f32_32x32x16_f16(a, b, c, 0, 0, 0);
}

__device__ inline u32 pk2u(float a, float b) {
    return __builtin_bit_cast(u32, __builtin_amdgcn_cvt_pkrtz(a, b));
}

// async global->LDS, 16 B per lane; LDS dest = wave-uniform base + lane*16B
__device__ inline void gl16(const f16* g, f16* l) {
    __builtin_amdgcn_global_load_lds(
        (const __attribute__((address_space(1))) void*)g,
        (__attribute__((address_space(3))) void*)l, 16, 0, 0);
}

// ---------------------------------------------------------------------------
// Kernel 1: merged prep. blocks [0,1536): weight norm -> w f16.
//           blocks [1536, 5632): transpose x (B,C,N) fp32 -> xT (B,N,C) f16.
// ---------------------------------------------------------------------------
__global__ __launch_bounds__(256) void prep_k(const float* __restrict__ pv,
                                              const float* __restrict__ pg,
                                              f16* __restrict__ w,
                                              const float* __restrict__ x,
                                              f16* __restrict__ xT) {
    int bid = blockIdx.x;
    if (bid < 1536) {
        int o = bid;
        const float* row = pv + (size_t)o * 512;
        float s = 0.f;
        for (int c = threadIdx.x; c < 512; c += 256) { float t = row[c]; s += t * t; }
        for (int off = 32; off; off >>= 1) s += __shfl_down(s, off, 64);
        __shared__ float red[4];
        int lane = threadIdx.x & 63, wid = threadIdx.x >> 6;
        if (lane == 0) red[wid] = s;
        __syncthreads();
        float tot = red[0] + red[1] + red[2] + red[3];
        float scale = pg[o] * rsqrtf(tot);
        for (int c = threadIdx.x; c < 512; c += 256)
            w[(size_t)o * 512 + c] = (f16)(row[c] * scale);
    } else {
        int t2 = bid - 1536;
        int n0 = (t2 & 31) * 32, c0 = ((t2 >> 5) & 15) * 32, b = t2 >> 9;
        int tx = threadIdx.x & 31, ty = threadIdx.x >> 5;  // 32 x 8
        __shared__ float t[32][33];
        const float* xb = x + (size_t)b * 512 * 1024;
        for (int i = 0; i < 4; i++)
            t[ty + 8 * i][tx] = xb[(size_t)(c0 + ty + 8 * i) * 1024 + n0 + tx];
        __syncthreads();
        f16* xTb = xT + (size_t)b * 1024 * 512;
        for (int i = 0; i < 4; i++)
            xTb[(size_t)(n0 + ty + 8 * i) * 512 + c0 + tx] = (f16)t[tx][ty + 8 * i];
    }
}

// ---------------------------------------------------------------------------
// Kernel 3: QKV GEMM (frozen R7 state): 32x32x16 MFMA, BK=64, staging via
//   global_load_lds_dwordx4, XOR swizzle pre-applied on the GLOBAL source.
// ---------------------------------------------------------------------------
__global__ __launch_bounds__(256) void qkv_gemm_k(const f16* __restrict__ w,
                                                  const f16* __restrict__ xT,
                                                  const float* __restrict__ pb,
                                                  f16* __restrict__ qk,
                                                  f16* __restrict__ v) {
    __shared__ f16 lA[128 * 64];   // 16 KB
    __shared__ f16 lB[128 * 64];   // 16 KB
    int b = blockIdx.z;
    int oBase = blockIdx.y * 128;
    int nBase = blockIdx.x * 128;
    const f16* xb = xT + (size_t)b * 1024 * 512;
    int tid = threadIdx.x, lane = tid & 63, warp = tid >> 6;
    int wy = warp >> 1, wx = warp & 1;
    int l31 = lane & 31, hi = lane >> 5;

    int srow = lane >> 3;
    int phys = lane & 7;
    int schunk = phys ^ srow;
    const f16* aS[4]; const f16* bS[4]; f16* dA[4]; f16* dB[4];
    for (int j = 0; j < 4; j++) {
        int rb = (warp * 4 + j) * 8;
        aS[j] = w  + (size_t)(oBase + rb + srow) * 512 + schunk * 8;
        bS[j] = xb + (size_t)(nBase + rb + srow) * 512 + schunk * 8;
        dA[j] = &lA[rb * 64];   // + lane*8 f16 done by HW (lane x 16 B)
        dB[j] = &lB[rb * 64];
    }
    int phk[4];
    for (int ks = 0; ks < 4; ks++)
        phk[ks] = (((ks * 2 + hi) ^ (l31 & 7))) * 8;

    f32x16 acc[2][2] = {};

    for (int i = 0; i < 8; i++) {
        int k0 = i * 64;
        __syncthreads();                 // prev tile's reads done
        for (int j = 0; j < 4; j++) {
            gl16(aS[j] + k0, dA[j]);
            gl16(bS[j] + k0, dB[j]);
        }
        __syncthreads();                 // implicit vmcnt(0) drain (m97)
        for (int ks = 0; ks < 4; ks++) {
            f16x8 af[2], bf[2];
            for (int mi = 0; mi < 2; mi++)
                af[mi] = *(f16x8*)&lA[(wy * 64 + mi * 32 + l31) * 64 + phk[ks]];
            for (int ni = 0; ni < 2; ni++)
                bf[ni] = *(f16x8*)&lB[(wx * 64 + ni * 32 + l31) * 64 + phk[ks]];
            for (int mi = 0; mi < 2; mi++)
                for (int ni = 0; ni < 2; ni++)
                    acc[mi][ni] = mfma32(af[mi], bf[ni], acc[mi][ni]);
        }
    }

    int selB = oBase >> 9;
    for (int mi = 0; mi < 2; mi++) {
        for (int g = 0; g < 4; g++) {
            int oR = oBase + wy * 64 + mi * 32 + 8 * g + 4 * hi;
            int h = (oR >> 6) & 7, d0 = oR & 63;
            for (int ni = 0; ni < 2; ni++) {
                int n = nBase + wx * 64 + ni * 32 + l31;
                if (selB < 2) {
                    float sc = selB == 0 ? 0.125f : 1.0f;  // fold 1/sqrt(64)
                    f16x4 o4;
                    for (int r = 0; r < 4; r++)
                        o4[r] = (f16)((acc[mi][ni][g * 4 + r] + pb[oR + r]) * sc);
                    *(f16x4*)&qk[((((size_t)b * 2 + selB) * 8 + h) * 1024 + n) * 64 + d0] = o4;
                } else {
                    for (int r = 0; r < 4; r++) {
                        float val = acc[mi][ni][g * 4 + r] + pb[oR + r];
                        v[(((size_t)b * 8 + h) * 64 + d0 + r) * 1024 + n] = (f16)val;
                    }
                }
            }
        }
    }
}

// ---------------------------------------------------------------------------
// Kernel 4: fused attention + residual.  v12 = R9 EXACTLY (best measured:
//   128.25 us total) + T5 setprio around the two MFMA clusters -- the only
//   unbundled untested low-risk technique (R11 tested it only bundled with
//   the KVBLK=128 regression; m191 measured +4-7% isolated on attn).
//   R9 structure: gl16-staged double-buffered K/V, ONE barrier per 64-kv
//   iteration, lane-linear [64][64] tiles, bank fix via pre-swizzled
//   GLOBAL source (m201 pattern), compute math bit-identical to R0.
// ---------------------------------------------------------------------------
#define TSZ 4096   // 64x64 f16 tile

__global__ __launch_bounds__(256, 2) void attn_k(const f16* __restrict__ qk,
                                                 const f16* __restrict__ vg,
                                                 const float* __restrict__ x,
                                                 float* __restrict__ out) {
    __shared__ __align__(16) f16 smem[4 * TSZ];   // [buf][K,V][64][64] = 32 KB
    int bh = blockIdx.y;
    int b = bh >> 3, h = bh & 7;
    int qBase = blockIdx.x * 128;
    int tid = threadIdx.x, lane = tid & 63, warp = tid >> 6;
    int l31 = lane & 31, hi = lane >> 5;

    const f16* qbase = qk + (((size_t)b * 2 + 0) * 8 + h) * 1024 * 64;
    const f16* kbase = qk + (((size_t)b * 2 + 1) * 8 + h) * 1024 * 64;
    const f16* vbase = vg + ((size_t)b * 8 + h) * 64 * 1024;

    int q0 = qBase + warp * 32;
    f16x8 aq[4];
    for (int ks = 0; ks < 4; ks++)
        aq[ks] = *(const f16x8*)&qbase[(size_t)(q0 + l31) * 64 + ks * 16 + hi * 8];

    // staging geometry: wave w covers rows [8w,8w+8) and [32+8w,32+8w+8)
    // of each 64x64 tile; lane -> (row 8w + lane>>3, phys chunk lane&7);
    // global chunk pre-swizzled: (lane&7) ^ (lane>>3)  [row&7 = lane>>3]
    int rb = lane >> 3;
    int gchunk = (lane & 7) ^ rb;
    const f16* kS0 = kbase + (size_t)(warp * 8 + rb) * 64 + gchunk * 8;
    const f16* vS0 = vbase + (size_t)(warp * 8 + rb) * 1024 + gchunk * 8;

    f32x16 accO[2] = {};
    float l_acc = 0.f;

#define STAGE(BUF, KT)                                                        \
    do {                                                                      \
        f16* lb = smem + (BUF) * 2 * TSZ;                                     \
        const f16* ks_ = kS0 + (size_t)(KT) * 4096;                           \
        const f16* vs_ = vS0 + (size_t)(KT) * 64;                             \
        gl16(ks_,             lb + warp * 512);                               \
        gl16(ks_ + 32 * 64,   lb + 2048 + warp * 512);                        \
        gl16(vs_,             lb + TSZ + warp * 512);                         \
        gl16(vs_ + 32 * 1024, lb + TSZ + 2048 + warp * 512);                  \
    } while (0)

    // prologue: tile 0 -> buf 0
    STAGE(0, 0);
    __syncthreads();   // implicit vmcnt(0): buf0 ready

    for (int kt = 0; kt < 16; kt++) {
        int cur = kt & 1;
        if (kt < 15) STAGE(cur ^ 1, kt + 1);   // async, lands by next barrier
        const f16* lK = smem + cur * 2 * TSZ;
        const f16* lV = lK + TSZ;

        // S^T per mt; p = exp(s) packed to f16x2 pairs in registers:
        // P0[mt][g] = k-pair {8g+4hi+0,1}, P1 = {8g+4hi+2,3} (col q = l31)
        u32 P0[2][4], P1[2][4];
        float rs = 0.f;
        for (int mt = 0; mt < 2; mt++) {
            f16x8 ak[4];
            for (int ks = 0; ks < 4; ks++) {
                int row = mt * 32 + l31;
                ak[ks] = *(const f16x8*)&lK[row * 64 + (((ks * 2 + hi) ^ (l31 & 7)) << 3)];
            }
            __builtin_amdgcn_s_setprio(1);
            f32x16 stt = {};
            for (int ks = 0; ks < 4; ks++)
                stt = mfma32(ak[ks], aq[ks], stt);
            __builtin_amdgcn_s_setprio(0);
            for (int g = 0; g < 4; g++) {
                float p0 = __expf(stt[g * 4 + 0]);
                float p1 = __expf(stt[g * 4 + 1]);
                float p2 = __expf(stt[g * 4 + 2]);
                float p3 = __expf(stt[g * 4 + 3]);
                rs += (p0 + p1) + (p2 + p3);
                P0[mt][g] = pk2u(p0, p1);
                P1[mt][g] = pk2u(p2, p3);
            }
        }
        l_acc += rs;

        // PV: B-frag for ks: mt=ks>>1; j0-3 from lane (q,0), j4-7 from (q,1),
        // both with g = 2(ks&1)+hi_dest.  Send g = 2(ks&1)+(hi^1).
        f16x8 av[2][4];
        for (int dt = 0; dt < 2; dt++)
            for (int ks = 0; ks < 4; ks++) {
                int row = dt * 32 + l31;
                av[dt][ks] = *(const f16x8*)&lV[row * 64 + (((ks * 2 + hi) ^ (l31 & 7)) << 3)];
            }
        f16x8 bfrag[4];
        for (int ks = 0; ks < 4; ks++) {
            int mt = ks >> 1, ge = 2 * (ks & 1);
            u32 e00 = P0[mt][ge], e01 = P0[mt][ge + 1];
            u32 e10 = P1[mt][ge], e11 = P1[mt][ge + 1];
            u32 k0 = hi ? e01 : e00;       // keep: g = ge + hi
            u32 k1 = hi ? e11 : e10;
            u32 s0 = hi ? e00 : e01;       // send: g = ge + (hi^1)
            u32 s1 = hi ? e10 : e11;
            u32 r0 = __shfl_xor(s0, 32, 64);
            u32 r1 = __shfl_xor(s1, 32, 64);
            u32 a0 = hi ? r0 : k0, a1 = hi ? r1 : k1;   // from (q,0)
            u32 b0 = hi ? k0 : r0, b1 = hi ? k1 : r1;   // from (q,1)
            u32x4 t = {a0, a1, b0, b1};
            bfrag[ks] = __builtin_bit_cast(f16x8, t);
        }
        __builtin_amdgcn_s_setprio(1);
        for (int dt = 0; dt < 2; dt++)
            for (int ks = 0; ks < 4; ks++)
                accO[dt] = mfma32(av[dt][ks], bfrag[ks], accO[dt]);
        __builtin_amdgcn_s_setprio(0);

        __syncthreads();   // reads of buf[cur] done; buf[cur^1] staged
    }
#undef STAGE

    // epilogue: l = own + partner halves; direct 2-segment coalesced stores
    float lt = l_acc + __shfl_xor(l_acc, 32, 64);
    float rl = 1.0f / lt;
    int q = q0 + l31;
    for (int dt = 0; dt < 2; dt++)
        for (int g = 0; g < 4; g++)
            for (int r = 0; r < 4; r++) {
                int d = dt * 32 + 8 * g + 4 * hi + r;
                size_t gi = ((size_t)b * 512 + h * 64 + d) * 1024 + q;
                out[gi] = x[gi] + accO[dt][g * 4 + r] * rl;
            }
}

// ---------------------------------------------------------------------------
extern "C" void kernel_launch(void* const* d_in, const int* in_sizes, int n_in,
                              void* d_out, int out_size, void* d_ws, size_t ws_size,
                              hipStream_t stream) {
    (void)in_sizes; (void)n_in; (void)out_size; (void)ws_size;
    const float* x  = (const float*)d_in[0];
    const float* pv = (const float*)d_in[1];
    const float* pg = (const float*)d_in[2];
    const float* pb = (const float*)d_in[3];
    float* out = (float*)d_out;

    char* ws = (char*)d_ws;
    f16* w   = (f16*)(ws);                                   // 1,572,864 B
    f16* xT  = (f16*)(ws + 1572864);                         // 8,388,608 B
    f16* qk  = (f16*)(ws + 1572864 + 8388608);               // 16,777,216 B
    f16* v   = (f16*)(ws + 1572864 + 8388608 + 16777216);    // 8,388,608 B

    hipLaunchKernelGGL(prep_k,     dim3(5632),     dim3(256), 0, stream, pv, pg, w, x, xT);
    hipLaunchKernelGGL(qkv_gemm_k, dim3(8, 12, 8), dim3(256), 0, stream, w, xT, pb, qk, v);
    hipLaunchKernelGGL(attn_k,     dim3(8, 64),    dim3(256), 0, stream, qk, v, x, out);
}

// Round 14
// 129.600 us; speedup vs baseline: 1.0442x; 1.0076x over previous
//
#include <hip/hip_runtime.h>

typedef _Float16 f16;
typedef _Float16 f16x2 __attribute__((ext_vector_type(2)));
typedef _Float16 f16x4 __attribute__((ext_vector_type(4)));
typedef _Float16 f16x8 __attribute__((ext_vector_type(8)));
typedef float f32x4 __attribute__((ext_vector_type(4)));
typedef float f32x16 __attribute__((ext_vector_type(16)));
typedef unsigned int u32;
typedef unsigned int u32x4 __attribute__((ext_vector_type(4)));

__device__ inline f32x16 mfma32(f16x8 a, f16x8 b, f32x16 c) {
    return __builtin_amdgcn_mfma_f32_32x32x16_f16(a, b, c, 0, 0, 0);
}

__device__ inline u32 pk2u(float a, float b) {
    return __builtin_bit_cast(u32, __builtin_amdgcn_cvt_pkrtz(a, b));
}

// async global->LDS, 16 B per lane; LDS dest = wave-uniform base + lane*16B
__device__ inline void gl16(const f16* g, f16* l) {
    __builtin_amdgcn_global_load_lds(
        (const __attribute__((address_space(1))) void*)g,
        (__attribute__((address_space(3))) void*)l, 16, 0, 0);
}

// ---------------------------------------------------------------------------
// Kernel 1: merged prep. blocks [0,1536): weight norm -> w f16.
//           blocks [1536, 5632): transpose x (B,C,N) fp32 -> xT (B,N,C) f16.
// ---------------------------------------------------------------------------
__global__ __launch_bounds__(256) void prep_k(const float* __restrict__ pv,
                                              const float* __restrict__ pg,
                                              f16* __restrict__ w,
                                              const float* __restrict__ x,
                                              f16* __restrict__ xT) {
    int bid = blockIdx.x;
    if (bid < 1536) {
        int o = bid;
        const float* row = pv + (size_t)o * 512;
        float s = 0.f;
        for (int c = threadIdx.x; c < 512; c += 256) { float t = row[c]; s += t * t; }
        for (int off = 32; off; off >>= 1) s += __shfl_down(s, off, 64);
        __shared__ float red[4];
        int lane = threadIdx.x & 63, wid = threadIdx.x >> 6;
        if (lane == 0) red[wid] = s;
        __syncthreads();
        float tot = red[0] + red[1] + red[2] + red[3];
        float scale = pg[o] * rsqrtf(tot);
        for (int c = threadIdx.x; c < 512; c += 256)
            w[(size_t)o * 512 + c] = (f16)(row[c] * scale);
    } else {
        int t2 = bid - 1536;
        int n0 = (t2 & 31) * 32, c0 = ((t2 >> 5) & 15) * 32, b = t2 >> 9;
        int tx = threadIdx.x & 31, ty = threadIdx.x >> 5;  // 32 x 8
        __shared__ float t[32][33];
        const float* xb = x + (size_t)b * 512 * 1024;
        for (int i = 0; i < 4; i++)
            t[ty + 8 * i][tx] = xb[(size_t)(c0 + ty + 8 * i) * 1024 + n0 + tx];
        __syncthreads();
        f16* xTb = xT + (size_t)b * 1024 * 512;
        for (int i = 0; i < 4; i++)
            xTb[(size_t)(n0 + ty + 8 * i) * 512 + c0 + tx] = (f16)t[tx][ty + 8 * i];
    }
}

// ---------------------------------------------------------------------------
// Kernel 3: QKV GEMM.  v13b: BK=32 DOUBLE-BUFFER, one barrier per K-step
//   (R13 retry: LDS pointer-array init replaced by per-use base compute --
//   the array initializer forced an unsupported addrspacecast).
//   Old schedule (barrier; issue gl16; drain-barrier; compute) gave the
//   staging loads ZERO latency cover (the m97 ~20% stall).  Now: stage
//   into the other buffer BEFORE compute, one barrier at the end ->
//   loads covered by the whole compute phase.  BK=32 keeps LDS at 32 KB
//   (2 buf x [A|B] x [128][32] f16) so occupancy is unchanged (m132's
//   BK=128 trap avoided).  Swizzle involution: LDS[r][p] holds global
//   chunk p^(r&3) (staged at cg=(lane&3)^(srow&3)); read at
//   p=(ks*2+hi)^(l31&3); row&3 = l31&3 -> retrieved chunk = ks*2+hi. ✓
//   128 MFMAs total, accumulator chaining and epilogue unchanged.
// ---------------------------------------------------------------------------
__global__ __launch_bounds__(256) void qkv_gemm_k(const f16* __restrict__ w,
                                                  const f16* __restrict__ xT,
                                                  const float* __restrict__ pb,
                                                  f16* __restrict__ qk,
                                                  f16* __restrict__ v) {
    __shared__ f16 smem[4 * 4096];   // [buf][A|B], each [128][32] = 8 KB
    int b = blockIdx.z;
    int oBase = blockIdx.y * 128;
    int nBase = blockIdx.x * 128;
    const f16* xb = xT + (size_t)b * 1024 * 512;
    int tid = threadIdx.x, lane = tid & 63, warp = tid >> 6;
    int wy = warp >> 1, wx = warp & 1;
    int l31 = lane & 31, hi = lane >> 5;

    // staging: instr (warp,j) covers rows [(warp*2+j)*16, +16) of a tile;
    // lane -> row offset lane>>2, phys chunk lane&3 (16B chunks along k);
    // global chunk pre-swizzled: (lane&3) ^ ((lane>>2)&3)  [= row&3]
    int srow = lane >> 2;
    int cg = (lane & 3) ^ (srow & 3);
    const f16* aS0 = w  + (size_t)(oBase + warp * 32 + srow) * 512 + cg * 8;
    const f16* aS1 = w  + (size_t)(oBase + warp * 32 + 16 + srow) * 512 + cg * 8;
    const f16* bS0 = xb + (size_t)(nBase + warp * 32 + srow) * 512 + cg * 8;
    const f16* bS1 = xb + (size_t)(nBase + warp * 32 + 16 + srow) * 512 + cg * 8;

#define QSTAGE(BUF, IT)                                                       \
    do {                                                                      \
        int k0_ = (IT) * 32;                                                  \
        f16* lAb = smem + (BUF) * 8192;                                       \
        f16* lBb = lAb + 4096;                                                \
        gl16(aS0 + k0_, lAb + (warp * 2 + 0) * 512);                          \
        gl16(aS1 + k0_, lAb + (warp * 2 + 1) * 512);                          \
        gl16(bS0 + k0_, lBb + (warp * 2 + 0) * 512);                          \
        gl16(bS1 + k0_, lBb + (warp * 2 + 1) * 512);                          \
    } while (0)

    f32x16 acc[2][2] = {};

    QSTAGE(0, 0);
    __syncthreads();                     // implicit vmcnt(0): buf0 ready

    for (int i = 0; i < 16; i++) {
        int cur = i & 1;
        if (i < 15) QSTAGE(cur ^ 1, i + 1);   // async, covered by compute
        const f16* lAc = smem + cur * 8192;
        const f16* lBc = lAc + 4096;
        for (int ks = 0; ks < 2; ks++) {
            f16x8 af[2], bf[2];
            for (int mi = 0; mi < 2; mi++) {
                int row = wy * 64 + mi * 32 + l31;
                af[mi] = *(const f16x8*)&lAc[row * 32 + (((ks * 2 + hi) ^ (l31 & 3)) * 8)];
            }
            for (int ni = 0; ni < 2; ni++) {
                int row = wx * 64 + ni * 32 + l31;
                bf[ni] = *(const f16x8*)&lBc[row * 32 + (((ks * 2 + hi) ^ (l31 & 3)) * 8)];
            }
            for (int mi = 0; mi < 2; mi++)
                for (int ni = 0; ni < 2; ni++)
                    acc[mi][ni] = mfma32(af[mi], bf[ni], acc[mi][ni]);
        }
        __syncthreads();                 // buf[cur] reads done; buf[cur^1] staged
    }
#undef QSTAGE

    int selB = oBase >> 9;
    for (int mi = 0; mi < 2; mi++) {
        for (int g = 0; g < 4; g++) {
            int oR = oBase + wy * 64 + mi * 32 + 8 * g + 4 * hi;
            int h = (oR >> 6) & 7, d0 = oR & 63;
            for (int ni = 0; ni < 2; ni++) {
                int n = nBase + wx * 64 + ni * 32 + l31;
                if (selB < 2) {
                    float sc = selB == 0 ? 0.125f : 1.0f;  // fold 1/sqrt(64)
                    f16x4 o4;
                    for (int r = 0; r < 4; r++)
                        o4[r] = (f16)((acc[mi][ni][g * 4 + r] + pb[oR + r]) * sc);
                    *(f16x4*)&qk[((((size_t)b * 2 + selB) * 8 + h) * 1024 + n) * 64 + d0] = o4;
                } else {
                    for (int r = 0; r < 4; r++) {
                        float val = acc[mi][ni][g * 4 + r] + pb[oR + r];
                        v[(((size_t)b * 8 + h) * 64 + d0 + r) * 1024 + n] = (f16)val;
                    }
                }
            }
        }
    }
}

// ---------------------------------------------------------------------------
// Kernel 4: fused attention + residual.  R9 EXACTLY (best measured state,
//   128.25 us total): gl16-staged double-buffered K/V, ONE barrier per
//   64-kv iteration, lane-linear [64][64] tiles, bank fix via pre-swizzled
//   GLOBAL source.  setprio removed (R12: null-to-negative).  FROZEN so
//   this round's delta attributes cleanly to qkv_gemm_k.
// ---------------------------------------------------------------------------
#define TSZ 4096   // 64x64 f16 tile

__global__ __launch_bounds__(256, 2) void attn_k(const f16* __restrict__ qk,
                                                 const f16* __restrict__ vg,
                                                 const float* __restrict__ x,
                                                 float* __restrict__ out) {
    __shared__ __align__(16) f16 smem[4 * TSZ];   // [buf][K,V][64][64] = 32 KB
    int bh = blockIdx.y;
    int b = bh >> 3, h = bh & 7;
    int qBase = blockIdx.x * 128;
    int tid = threadIdx.x, lane = tid & 63, warp = tid >> 6;
    int l31 = lane & 31, hi = lane >> 5;

    const f16* qbase = qk + (((size_t)b * 2 + 0) * 8 + h) * 1024 * 64;
    const f16* kbase = qk + (((size_t)b * 2 + 1) * 8 + h) * 1024 * 64;
    const f16* vbase = vg + ((size_t)b * 8 + h) * 64 * 1024;

    int q0 = qBase + warp * 32;
    f16x8 aq[4];
    for (int ks = 0; ks < 4; ks++)
        aq[ks] = *(const f16x8*)&qbase[(size_t)(q0 + l31) * 64 + ks * 16 + hi * 8];

    // staging geometry: wave w covers rows [8w,8w+8) and [32+8w,32+8w+8)
    // of each 64x64 tile; lane -> (row 8w + lane>>3, phys chunk lane&7);
    // global chunk pre-swizzled: (lane&7) ^ (lane>>3)  [row&7 = lane>>3]
    int rb = lane >> 3;
    int gchunk = (lane & 7) ^ rb;
    const f16* kS0 = kbase + (size_t)(warp * 8 + rb) * 64 + gchunk * 8;
    const f16* vS0 = vbase + (size_t)(warp * 8 + rb) * 1024 + gchunk * 8;

    f32x16 accO[2] = {};
    float l_acc = 0.f;

#define STAGE(BUF, KT)                                                        \
    do {                                                                      \
        f16* lb = smem + (BUF) * 2 * TSZ;                                     \
        const f16* ks_ = kS0 + (size_t)(KT) * 4096;                           \
        const f16* vs_ = vS0 + (size_t)(KT) * 64;                             \
        gl16(ks_,             lb + warp * 512);                               \
        gl16(ks_ + 32 * 64,   lb + 2048 + warp * 512);                        \
        gl16(vs_,             lb + TSZ + warp * 512);                         \
        gl16(vs_ + 32 * 1024, lb + TSZ + 2048 + warp * 512);                  \
    } while (0)

    // prologue: tile 0 -> buf 0
    STAGE(0, 0);
    __syncthreads();   // implicit vmcnt(0): buf0 ready

    for (int kt = 0; kt < 16; kt++) {
        int cur = kt & 1;
        if (kt < 15) STAGE(cur ^ 1, kt + 1);   // async, lands by next barrier
        const f16* lK = smem + cur * 2 * TSZ;
        const f16* lV = lK + TSZ;

        // S^T per mt; p = exp(s) packed to f16x2 pairs in registers:
        // P0[mt][g] = k-pair {8g+4hi+0,1}, P1 = {8g+4hi+2,3} (col q = l31)
        u32 P0[2][4], P1[2][4];
        float rs = 0.f;
        for (int mt = 0; mt < 2; mt++) {
            f16x8 ak[4];
            for (int ks = 0; ks < 4; ks++) {
                int row = mt * 32 + l31;
                ak[ks] = *(const f16x8*)&lK[row * 64 + (((ks * 2 + hi) ^ (l31 & 7)) << 3)];
            }
            f32x16 stt = {};
            for (int ks = 0; ks < 4; ks++)
                stt = mfma32(ak[ks], aq[ks], stt);
            for (int g = 0; g < 4; g++) {
                float p0 = __expf(stt[g * 4 + 0]);
                float p1 = __expf(stt[g * 4 + 1]);
                float p2 = __expf(stt[g * 4 + 2]);
                float p3 = __expf(stt[g * 4 + 3]);
                rs += (p0 + p1) + (p2 + p3);
                P0[mt][g] = pk2u(p0, p1);
                P1[mt][g] = pk2u(p2, p3);
            }
        }
        l_acc += rs;

        // PV: B-frag for ks: mt=ks>>1; j0-3 from lane (q,0), j4-7 from (q,1),
        // both with g = 2(ks&1)+hi_dest.  Send g = 2(ks&1)+(hi^1).
        f16x8 av[2][4];
        for (int dt = 0; dt < 2; dt++)
            for (int ks = 0; ks < 4; ks++) {
                int row = dt * 32 + l31;
                av[dt][ks] = *(const f16x8*)&lV[row * 64 + (((ks * 2 + hi) ^ (l31 & 7)) << 3)];
            }
        f16x8 bfrag[4];
        for (int ks = 0; ks < 4; ks++) {
            int mt = ks >> 1, ge = 2 * (ks & 1);
            u32 e00 = P0[mt][ge], e01 = P0[mt][ge + 1];
            u32 e10 = P1[mt][ge], e11 = P1[mt][ge + 1];
            u32 k0 = hi ? e01 : e00;       // keep: g = ge + hi
            u32 k1 = hi ? e11 : e10;
            u32 s0 = hi ? e00 : e01;       // send: g = ge + (hi^1)
            u32 s1 = hi ? e10 : e11;
            u32 r0 = __shfl_xor(s0, 32, 64);
            u32 r1 = __shfl_xor(s1, 32, 64);
            u32 a0 = hi ? r0 : k0, a1 = hi ? r1 : k1;   // from (q,0)
            u32 b0 = hi ? k0 : r0, b1 = hi ? k1 : r1;   // from (q,1)
            u32x4 t = {a0, a1, b0, b1};
            bfrag[ks] = __builtin_bit_cast(f16x8, t);
        }
        for (int dt = 0; dt < 2; dt++)
            for (int ks = 0; ks < 4; ks++)
                accO[dt] = mfma32(av[dt][ks], bfrag[ks], accO[dt]);

        __syncthreads();   // reads of buf[cur] done; buf[cur^1] staged
    }
#undef STAGE

    // epilogue: l = own + partner halves; direct 2-segment coalesced stores
    float lt = l_acc + __shfl_xor(l_acc, 32, 64);
    float rl = 1.0f / lt;
    int q = q0 + l31;
    for (int dt = 0; dt < 2; dt++)
        for (int g = 0; g < 4; g++)
            for (int r = 0; r < 4; r++) {
                int d = dt * 32 + 8 * g + 4 * hi + r;
                size_t gi = ((size_t)b * 512 + h * 64 + d) * 1024 + q;
                out[gi] = x[gi] + accO[dt][g * 4 + r] * rl;
            }
}

// ---------------------------------------------------------------------------
extern "C" void kernel_launch(void* const* d_in, const int* in_sizes, int n_in,
                              void* d_out, int out_size, void* d_ws, size_t ws_size,
                              hipStream_t stream) {
    (void)in_sizes; (void)n_in; (void)out_size; (void)ws_size;
    const float* x  = (const float*)d_in[0];
    const float* pv = (const float*)d_in[1];
    const float* pg = (const float*)d_in[2];
    const float* pb = (const float*)d_in[3];
    float* out = (float*)d_out;

    char* ws = (char*)d_ws;
    f16* w   = (f16*)(ws);                                   // 1,572,864 B
    f16* xT  = (f16*)(ws + 1572864);                         // 8,388,608 B
    f16* qk  = (f16*)(ws + 1572864 + 8388608);               // 16,777,216 B
    f16* v   = (f16*)(ws + 1572864 + 8388608 + 16777216);    // 8,388,608 B

    hipLaunchKernelGGL(prep_k,     dim3(5632),     dim3(256), 0, stream, pv, pg, w, x, xT);
    hipLaunchKernelGGL(qkv_gemm_k, dim3(8, 12, 8), dim3(256), 0, stream, w, xT, pb, qk, v);
    hipLaunchKernelGGL(attn_k,     dim3(8, 64),    dim3(256), 0, stream, qk, v, x, out);
}